// Round 1
// baseline (2142.131 us; speedup 1.0000x reference)
//
#include <hip/hip_runtime.h>
#include <hip/hip_bf16.h>

#define HID 256
#define NHD 8

// ---------------- GEMM: C[M,Nc] = act(A[M,K] @ B[K,Nc] + bias (+C)) ----------------
template<int ACT, bool OUTBF, bool ACC>
__global__ __launch_bounds__(256)
void gemm_k(const float* __restrict__ A, const float* __restrict__ B,
            const float* __restrict__ bias, float* __restrict__ Cf,
            __hip_bfloat16* __restrict__ Cb, int M, int Nc, int K)
{
    __shared__ float As[16][65];
    __shared__ float Bs[16][65];
    const int tx = threadIdx.x, ty = threadIdx.y;
    const int tid = ty * 16 + tx;
    const int row0 = blockIdx.y * 64, col0 = blockIdx.x * 64;
    float acc[4][4] = {};
    const int a_row = tid >> 2;         // 0..63
    const int a_k   = (tid & 3) * 4;    // 0,4,8,12
    const int b_k   = tid >> 4;         // 0..15
    const int b_col = (tid & 15) * 4;   // 0..60
    for (int k0 = 0; k0 < K; k0 += 16) {
        const int ar = row0 + a_row;
        #pragma unroll
        for (int i = 0; i < 4; ++i) {
            int kk = k0 + a_k + i;
            As[a_k + i][a_row] = (ar < M && kk < K) ? A[(long)ar * K + kk] : 0.f;
        }
        const int bk = k0 + b_k;
        #pragma unroll
        for (int i = 0; i < 4; ++i) {
            int bc = col0 + b_col + i;
            Bs[b_k][b_col + i] = (bk < K) ? B[(long)bk * Nc + bc] : 0.f;
        }
        __syncthreads();
        #pragma unroll
        for (int kk = 0; kk < 16; ++kk) {
            float a[4], b[4];
            #pragma unroll
            for (int i = 0; i < 4; ++i) a[i] = As[kk][ty * 4 + i];
            #pragma unroll
            for (int j = 0; j < 4; ++j) b[j] = Bs[kk][tx * 4 + j];
            #pragma unroll
            for (int i = 0; i < 4; ++i)
                #pragma unroll
                for (int j = 0; j < 4; ++j)
                    acc[i][j] = fmaf(a[i], b[j], acc[i][j]);
        }
        __syncthreads();
    }
    #pragma unroll
    for (int i = 0; i < 4; ++i) {
        const int r = row0 + ty * 4 + i;
        if (r >= M) continue;
        #pragma unroll
        for (int j = 0; j < 4; ++j) {
            const int c = col0 + tx * 4 + j;
            float v = acc[i][j];
            if (bias) v += bias[c];
            if (ACC) v += Cf[(long)r * Nc + c];
            if (ACT == 1) v = v > 0.f ? v : 0.f;
            if (OUTBF) Cb[(long)r * Nc + c] = __float2bfloat16(v);
            else       Cf[(long)r * Nc + c] = v;
        }
    }
}

// ---------------- attention logits: als/ald[n,h] = sum_c xf[n,h,c] * a[h,c] ----------------
template<bool BF>
__global__ void attn_logits_k(const void* __restrict__ xf_, const float* __restrict__ a_s,
                              const float* __restrict__ a_d, float* __restrict__ als,
                              float* __restrict__ ald, int N, int Cc)
{
    int nh = blockIdx.x * blockDim.x + threadIdx.x;
    if (nh >= N * NHD) return;
    int n = nh >> 3, h = nh & 7;
    const float* asp = a_s + h * Cc;
    const float* adp = a_d + h * Cc;
    float s = 0.f, d = 0.f;
    if (BF) {
        const __hip_bfloat16* xp = (const __hip_bfloat16*)xf_ + (long)n * NHD * Cc + h * Cc;
        for (int c = 0; c < Cc; ++c) { float v = __bfloat162float(xp[c]); s += v * asp[c]; d += v * adp[c]; }
    } else {
        const float* xp = (const float*)xf_ + (long)n * NHD * Cc + h * Cc;
        for (int c = 0; c < Cc; ++c) { float v = xp[c]; s += v * asp[c]; d += v * adp[c]; }
    }
    als[nh] = s; ald[nh] = d;
}

// ---------------- init: mbuf=enc(-inf), den=0, agg=0, stats=0 ----------------
__global__ void init_k(unsigned* __restrict__ mbuf, float* __restrict__ den,
                       float* __restrict__ agg, float* __restrict__ stats,
                       int nh, long na)
{
    long i = (long)blockIdx.x * blockDim.x + threadIdx.x;
    if (i < na) agg[i] = 0.f;
    if (i < nh) { mbuf[i] = 0x007FFFFFu; den[i] = 0.f; }
    if (i < 512) stats[i] = 0.f;
}

__device__ __forceinline__ unsigned enc_f32(float f) {
    unsigned u = __float_as_uint(f);
    return (u & 0x80000000u) ? ~u : (u | 0x80000000u);
}

// ---------------- per-edge score (leaky-relu) + segment max ----------------
__global__ void edge_score_max_k(const int* __restrict__ ei, const float* __restrict__ als,
                                 const float* __restrict__ ald, float* __restrict__ ebuf,
                                 unsigned* __restrict__ mbuf, int E, int N)
{
    int eid = blockIdx.x * blockDim.x + threadIdx.x;
    if (eid >= E + N) return;
    int src = eid < E ? ei[eid] : eid - E;
    int dst = eid < E ? ei[E + eid] : eid - E;
    #pragma unroll
    for (int h = 0; h < NHD; ++h) {
        float e = als[src * NHD + h] + ald[dst * NHD + h];
        e = e > 0.f ? e : 0.2f * e;
        ebuf[(long)eid * NHD + h] = e;
        atomicMax(&mbuf[dst * NHD + h], enc_f32(e));
    }
}

__global__ void decode_max_k(unsigned* __restrict__ mbuf, int nh)
{
    int i = blockIdx.x * blockDim.x + threadIdx.x;
    if (i >= nh) return;
    unsigned u = mbuf[i];
    u = (u & 0x80000000u) ? (u & 0x7FFFFFFFu) : ~u;
    ((float*)mbuf)[i] = __uint_as_float(u);
}

// ---------------- ex = exp(e - m[dst]); den[dst] += ex ----------------
__global__ void edge_exp_k(const int* __restrict__ ei, const float* __restrict__ mf,
                           float* __restrict__ ebuf, float* __restrict__ den, int E, int N)
{
    int eid = blockIdx.x * blockDim.x + threadIdx.x;
    if (eid >= E + N) return;
    int dst = eid < E ? ei[E + eid] : eid - E;
    #pragma unroll
    for (int h = 0; h < NHD; ++h) {
        float ex = __expf(ebuf[(long)eid * NHD + h] - mf[dst * NHD + h]);
        ebuf[(long)eid * NHD + h] = ex;
        atomicAdd(&den[dst * NHD + h], ex);
    }
}

// ---------------- aggregation, concat layers (C=32, f32 features) ----------------
__global__ __launch_bounds__(256)
void agg_cat_k(const int* __restrict__ ei, const float* __restrict__ xf,
               const float* __restrict__ ebuf, const float* __restrict__ den,
               float* __restrict__ agg, int E, int N)
{
    int eid = blockIdx.x;
    int tid = threadIdx.x;              // 0..255 = h*32+c
    int src = eid < E ? ei[eid] : eid - E;
    int dst = eid < E ? ei[E + eid] : eid - E;
    int h = tid >> 5;
    float alpha = ebuf[(long)eid * NHD + h] / (den[dst * NHD + h] + 1e-16f);
    float v = xf[(long)src * HID + tid] * alpha;
    atomicAdd(&agg[(long)dst * HID + tid], v);
}

// ---------------- aggregation, mean layer (C=256, bf16 features, head-reduced) ----------------
__global__ __launch_bounds__(256)
void agg_mean_k(const int* __restrict__ ei, const __hip_bfloat16* __restrict__ xf,
                const float* __restrict__ ebuf, const float* __restrict__ den,
                float* __restrict__ agg, int E, int N)
{
    __shared__ float al[NHD];
    int eid = blockIdx.x;
    int tid = threadIdx.x;              // channel 0..255
    int src = eid < E ? ei[eid] : eid - E;
    int dst = eid < E ? ei[E + eid] : eid - E;
    if (tid < NHD) al[tid] = ebuf[(long)eid * NHD + tid] / (den[dst * NHD + tid] + 1e-16f);
    __syncthreads();
    const __hip_bfloat16* xp = xf + (long)src * (NHD * HID);
    float s = 0.f;
    #pragma unroll
    for (int h = 0; h < NHD; ++h)
        s += al[h] * __bfloat162float(xp[h * HID + tid]);
    atomicAdd(&agg[(long)dst * HID + tid], s * 0.125f);
}

// ---------------- BN stats: per-channel partial sums of (v+bias), (v+bias)^2 ----------------
__global__ __launch_bounds__(256)
void stats_k(const float* __restrict__ agg, const float* __restrict__ bias,
             float* __restrict__ stats, int N)
{
    int c = threadIdx.x;
    int r0 = blockIdx.x * 100;
    int rend = r0 + 100; if (rend > N) rend = N;
    float b = bias[c];
    float s0 = 0.f, s1 = 0.f;
    for (int r = r0; r < rend; ++r) {
        float v = agg[(long)r * HID + c] + b;
        s0 += v; s1 += v * v;
    }
    atomicAdd(&stats[c], s0);
    atomicAdd(&stats[HID + c], s1);
}

__global__ void bnfin_k(float* __restrict__ stats, int N)
{
    int c = threadIdx.x;
    float mean = stats[c] / N;
    float var = stats[HID + c] / N - mean * mean;
    stats[c] = mean;
    stats[HID + c] = rsqrtf(var + 1e-5f);
}

// ---------------- BN apply (+bias) [+ELU +residual] ----------------
template<bool ELU_RES>
__global__ void bnapply_k(const float* __restrict__ agg, const float* __restrict__ bias,
                          const float* __restrict__ stats, const float* __restrict__ g,
                          const float* __restrict__ be, const float* __restrict__ hprev,
                          float* __restrict__ hout, int N)
{
    long i = (long)blockIdx.x * blockDim.x + threadIdx.x;
    if (i >= (long)N * HID) return;
    int c = (int)(i & (HID - 1));
    float v = agg[i] + bias[c];
    v = (v - stats[c]) * stats[HID + c] * g[c] + be[c];
    if (ELU_RES) {
        v = v > 0.f ? v : (__expf(v) - 1.f);
        v += hprev[i];
    }
    hout[i] = v;
}

// ---------------- final tiny GEMM: out[N,2] = z2[N,128] @ W3[128,2] + b3 ----------------
__global__ void final_k(const float* __restrict__ z2, const float* __restrict__ W,
                        const float* __restrict__ b, float* __restrict__ out, int N)
{
    int n = blockIdx.x * blockDim.x + threadIdx.x;
    if (n >= N) return;
    float a0 = b[0], a1 = b[1];
    const float* zp = z2 + (long)n * 128;
    #pragma unroll 4
    for (int k = 0; k < 128; ++k) { float z = zp[k]; a0 += z * W[k * 2]; a1 += z * W[k * 2 + 1]; }
    out[n * 2] = a0; out[n * 2 + 1] = a1;
}

extern "C" void kernel_launch(void* const* d_in, const int* in_sizes, int n_in,
                              void* d_out, int out_size, void* d_ws, size_t ws_size,
                              hipStream_t stream)
{
    const float* x   = (const float*)d_in[0];
    const int*   ei  = (const int*)d_in[1];
    const float* Wp  = (const float*)d_in[2];
    const float* bp  = (const float*)d_in[3];
    const float* W[3]   = {(const float*)d_in[4],  (const float*)d_in[10], (const float*)d_in[16]};
    const float* Asv[3] = {(const float*)d_in[5],  (const float*)d_in[11], (const float*)d_in[17]};
    const float* Adv[3] = {(const float*)d_in[6],  (const float*)d_in[12], (const float*)d_in[18]};
    const float* Bb[3]  = {(const float*)d_in[7],  (const float*)d_in[13], (const float*)d_in[19]};
    const float* Gg[3]  = {(const float*)d_in[8],  (const float*)d_in[14], (const float*)d_in[20]};
    const float* Be[3]  = {(const float*)d_in[9],  (const float*)d_in[15], (const float*)d_in[21]};
    const float* cW1 = (const float*)d_in[22];
    const float* cb1 = (const float*)d_in[23];
    const float* cW2 = (const float*)d_in[24];
    const float* cb2 = (const float*)d_in[25];
    const float* cW3 = (const float*)d_in[26];
    const float* cb3 = (const float*)d_in[27];

    const int F = in_sizes[2] / HID;      // 236
    const int N = in_sizes[0] / F;        // 20000
    const int E = in_sizes[1] / 2;        // 160000
    const int EP = E + N;

    float* ws  = (float*)d_ws;
    float* H0   = ws;                          // h_temporal  [N,256]
    float* H1   = H0 + (long)N * HID;          // [N,256]
    float* H2   = H1 + (long)N * HID;          // [N,256]
    float* AGG  = H2 + (long)N * HID;          // [N,256]
    float* ALS  = AGG + (long)N * HID;         // [N,8]
    float* ALD  = ALS + (long)N * NHD;
    float* MBUF = ALD + (long)N * NHD;         // encoded max -> decoded float
    float* DEN  = MBUF + (long)N * NHD;
    float* EXF  = DEN + (long)N * NHD;         // [E',8] e -> ex
    float* STATS= EXF + (long)EP * NHD;        // 512
    float* Z2   = STATS + 512;                 // [N,128]
    float* XFf  = (float*)(Z2 + (long)N * 128);           // layers 0/1: f32 [N,256]
    __hip_bfloat16* XFb = (__hip_bfloat16*)XFf;           // layer 2: bf16 [N,2048]

    const dim3 blk2(16, 16);
    const int mtiles = (N + 63) / 64;
    const int nhBlocks = (N * NHD + 255) / 256;
    const int naBlocks = (int)(((long)N * HID + 255) / 256);
    const int epBlocks = (EP + 255) / 256;
    const int statBlocks = (N + 99) / 100;

    // 1. input projection: H0 = x @ Wp + bp   (h_temporal)
    gemm_k<0,false,false><<<dim3(HID/64, mtiles), blk2, 0, stream>>>(x, Wp, bp, H0, nullptr, N, HID, F);

    // 2. GAT layers 0,1 (concat=True) + BN + ELU + residual
    const float* Hin = H0;
    float* Houts[2] = {H1, H2};
    for (int L = 0; L < 2; ++L) {
        float* Hout = Houts[L];
        gemm_k<0,false,false><<<dim3(HID/64, mtiles), blk2, 0, stream>>>(Hin, W[L], nullptr, XFf, nullptr, N, HID, HID);
        attn_logits_k<false><<<nhBlocks, 256, 0, stream>>>(XFf, Asv[L], Adv[L], ALS, ALD, N, 32);
        init_k<<<naBlocks, 256, 0, stream>>>((unsigned*)MBUF, DEN, AGG, STATS, N * NHD, (long)N * HID);
        edge_score_max_k<<<epBlocks, 256, 0, stream>>>(ei, ALS, ALD, EXF, (unsigned*)MBUF, E, N);
        decode_max_k<<<nhBlocks, 256, 0, stream>>>((unsigned*)MBUF, N * NHD);
        edge_exp_k<<<epBlocks, 256, 0, stream>>>(ei, MBUF, EXF, DEN, E, N);
        agg_cat_k<<<EP, 256, 0, stream>>>(ei, XFf, EXF, DEN, AGG, E, N);
        stats_k<<<statBlocks, 256, 0, stream>>>(AGG, Bb[L], STATS, N);
        bnfin_k<<<1, 256, 0, stream>>>(STATS, N);
        bnapply_k<true><<<naBlocks, 256, 0, stream>>>(AGG, Bb[L], STATS, Gg[L], Be[L], Hin, Hout, N);
        Hin = Hout;
    }

    // 3. GAT layer 2 (concat=False -> mean over heads) + BN
    gemm_k<0,true,false><<<dim3(2048/64, mtiles), blk2, 0, stream>>>(H2, W[2], nullptr, nullptr, XFb, N, 2048, HID);
    attn_logits_k<true><<<nhBlocks, 256, 0, stream>>>(XFb, Asv[2], Adv[2], ALS, ALD, N, 256);
    init_k<<<naBlocks, 256, 0, stream>>>((unsigned*)MBUF, DEN, AGG, STATS, N * NHD, (long)N * HID);
    edge_score_max_k<<<epBlocks, 256, 0, stream>>>(ei, ALS, ALD, EXF, (unsigned*)MBUF, E, N);
    decode_max_k<<<nhBlocks, 256, 0, stream>>>((unsigned*)MBUF, N * NHD);
    edge_exp_k<<<epBlocks, 256, 0, stream>>>(ei, MBUF, EXF, DEN, E, N);
    agg_mean_k<<<EP, 256, 0, stream>>>(ei, XFb, EXF, DEN, AGG, E, N);
    stats_k<<<statBlocks, 256, 0, stream>>>(AGG, Bb[2], STATS, N);
    bnfin_k<<<1, 256, 0, stream>>>(STATS, N);
    bnapply_k<false><<<naBlocks, 256, 0, stream>>>(AGG, Bb[2], STATS, Gg[2], Be[2], nullptr, H1, N);

    // 4. classifier: hc = [h3(H1), h_temporal(H0)]; z1 = relu(hc@cW1+cb1) -> H2
    gemm_k<0,false,false><<<dim3(HID/64, mtiles), blk2, 0, stream>>>(H1, cW1, cb1, H2, nullptr, N, HID, HID);
    gemm_k<1,false,true ><<<dim3(HID/64, mtiles), blk2, 0, stream>>>(H0, cW1 + (long)HID * HID, nullptr, H2, nullptr, N, HID, HID);
    // z2 = relu(z1@cW2+cb2) -> Z2
    gemm_k<1,false,false><<<dim3(2, mtiles), blk2, 0, stream>>>(H2, cW2, cb2, Z2, nullptr, N, 128, HID);
    // out = z2@cW3+cb3
    final_k<<<(N + 255) / 256, 256, 0, stream>>>(Z2, cW3, cb3, (float*)d_out, N);
}

// Round 2
// 1274.682 us; speedup vs baseline: 1.6805x; 1.6805x over previous
//
#include <hip/hip_runtime.h>
#include <hip/hip_bf16.h>

#define HID 256
#define NHD 8

typedef short short8 __attribute__((ext_vector_type(8)));
typedef float f32x4 __attribute__((ext_vector_type(4)));

__device__ __forceinline__ float b2f(unsigned short u) {
    return __uint_as_float(((unsigned)u) << 16);
}
__device__ __forceinline__ unsigned short f2b(float f) {
    __hip_bfloat16 h = __float2bfloat16(f);
    return *reinterpret_cast<unsigned short*>(&h);
}

// ---------------- weight convert+transpose: WT[n*Kpad+k] = bf16(W[k*Nc+n]) ----------------
__global__ void cvtT_k(const float* __restrict__ W, unsigned short* __restrict__ WT,
                       int K, int Kpad, int Nc)
{
    long i = (long)blockIdx.x * blockDim.x + threadIdx.x;
    if (i >= (long)Nc * Kpad) return;
    int n = (int)(i / Kpad), k = (int)(i % Kpad);
    WT[i] = (k < K) ? f2b(W[(long)k * Nc + n]) : (unsigned short)0;
}

// ---------------- x convert with row pad ----------------
__global__ void cvtx_k(const float* __restrict__ x, unsigned short* __restrict__ xb,
                       int N, int F, int Fpad)
{
    long i = (long)blockIdx.x * blockDim.x + threadIdx.x;
    if (i >= (long)N * Fpad) return;
    int r = (int)(i / Fpad), c = (int)(i % Fpad);
    xb[i] = (c < F) ? f2b(x[(long)r * F + c]) : (unsigned short)0;
}

// ---------------- MFMA GEMM: C[M,Nc] = A[M,K](bf16) @ BT[Nc,K](bf16)^T ----------------
// 128x128 tile, 4 waves (2x2), each wave 64x64 via 4x4 frags of 16x16x32.
// LDS XOR-swizzled (ushort idx ^ ((row&7)<<3)) to kill stride-64B bank conflicts.
template<bool BIAS, bool RELU, bool OUTF, bool OUTB>
__global__ __launch_bounds__(256)
void mgemm_k(const unsigned short* __restrict__ A, int lda,
             const unsigned short* __restrict__ BT,
             const float* __restrict__ bias,
             float* __restrict__ Cf, int ldf,
             unsigned short* __restrict__ Cb, int ldb,
             int M, int Nc, int K)
{
    __shared__ unsigned short As[128 * 32];
    __shared__ unsigned short Bs[128 * 32];
    const int tid = threadIdx.x;
    const int lane = tid & 63, wid = tid >> 6;
    const int wm = wid >> 1, wn = wid & 1;
    const int lr = lane & 15, lg = lane >> 4;
    const int row0 = blockIdx.y * 128, col0 = blockIdx.x * 128;
    f32x4 acc[4][4] = {};

    for (int k0 = 0; k0 < K; k0 += 32) {
        __syncthreads();
        #pragma unroll
        for (int c = 0; c < 2; ++c) {
            int chunk = tid * 2 + c;
            int r = chunk >> 2, kc = (chunk & 3) * 8;
            int idx = (r * 32 + kc) ^ ((r & 7) << 3);
            int gk = k0 + kc;
            // A chunk
            int gr = row0 + r;
            int4 va;
            if (gr < M && gk + 8 <= K) va = *(const int4*)(A + (long)gr * lda + gk);
            else {
                unsigned short tmp[8];
                #pragma unroll
                for (int j = 0; j < 8; ++j)
                    tmp[j] = (gr < M && gk + j < K) ? A[(long)gr * lda + gk + j] : (unsigned short)0;
                va = *(const int4*)tmp;
            }
            *(int4*)(&As[idx]) = va;
            // B chunk (BT row = output column)
            int gn = col0 + r;
            int4 vb;
            if (gk + 8 <= K) vb = *(const int4*)(BT + (long)gn * K + gk);
            else {
                unsigned short tmp[8];
                #pragma unroll
                for (int j = 0; j < 8; ++j)
                    tmp[j] = (gk + j < K) ? BT[(long)gn * K + gk + j] : (unsigned short)0;
                vb = *(const int4*)tmp;
            }
            *(int4*)(&Bs[idx]) = vb;
        }
        __syncthreads();
        short8 af[4], bfr[4];
        #pragma unroll
        for (int m = 0; m < 4; ++m) {
            int row = wm * 64 + m * 16 + lr;
            int idx = (row * 32 + lg * 8) ^ ((row & 7) << 3);
            af[m] = *(const short8*)(&As[idx]);
        }
        #pragma unroll
        for (int n = 0; n < 4; ++n) {
            int rowb = wn * 64 + n * 16 + lr;
            int idx = (rowb * 32 + lg * 8) ^ ((rowb & 7) << 3);
            bfr[n] = *(const short8*)(&Bs[idx]);
        }
        #pragma unroll
        for (int m = 0; m < 4; ++m)
            #pragma unroll
            for (int n = 0; n < 4; ++n)
                acc[m][n] = __builtin_amdgcn_mfma_f32_16x16x32_bf16(af[m], bfr[n], acc[m][n], 0, 0, 0);
    }
    // epilogue: C/D layout col=lane&15, row=(lane>>4)*4+reg
    #pragma unroll
    for (int m = 0; m < 4; ++m) {
        #pragma unroll
        for (int i = 0; i < 4; ++i) {
            int row = row0 + wm * 64 + m * 16 + lg * 4 + i;
            if (row >= M) continue;
            #pragma unroll
            for (int n = 0; n < 4; ++n) {
                int col = col0 + wn * 64 + n * 16 + lr;
                float v = acc[m][n][i];
                if (BIAS) v += bias[col];
                if (RELU) v = v > 0.f ? v : 0.f;
                if (OUTF) Cf[(long)row * ldf + col] = v;
                if (OUTB) Cb[(long)row * ldb + col] = f2b(v);
            }
        }
    }
}

// ---------------- attention logits (bf16 features): als/ald[n,h] = sum_c x[n,h,c]*a[h,c] ----------------
__global__ void attn_logits_k(const unsigned short* __restrict__ xf, const float* __restrict__ a_s,
                              const float* __restrict__ a_d, float* __restrict__ als,
                              float* __restrict__ ald, int N, int Cc)
{
    int nh = blockIdx.x * blockDim.x + threadIdx.x;
    if (nh >= N * NHD) return;
    int n = nh >> 3, h = nh & 7;
    const unsigned short* xp = xf + (long)n * NHD * Cc + h * Cc;
    const float* asp = a_s + h * Cc;
    const float* adp = a_d + h * Cc;
    float s = 0.f, d = 0.f;
    for (int c = 0; c < Cc; c += 8) {
        short8 v = *(const short8*)(xp + c);
        #pragma unroll
        for (int j = 0; j < 8; ++j) {
            float f = b2f((unsigned short)v[j]);
            s += f * asp[c + j]; d += f * adp[c + j];
        }
    }
    als[nh] = s; ald[nh] = d;
}

// ---------------- init ----------------
__global__ void init_k(unsigned* __restrict__ mbuf, float* __restrict__ den,
                       float* __restrict__ agg, float* __restrict__ stats,
                       int nh, long na)
{
    long i = (long)blockIdx.x * blockDim.x + threadIdx.x;
    if (i < na) agg[i] = 0.f;
    if (i < nh) { mbuf[i] = 0x007FFFFFu; den[i] = 0.f; }
    if (i < 512) stats[i] = 0.f;
}

__device__ __forceinline__ unsigned enc_f32(float f) {
    unsigned u = __float_as_uint(f);
    return (u & 0x80000000u) ? ~u : (u | 0x80000000u);
}

// ---------------- per-edge score (leaky-relu) + segment max ----------------
__global__ void edge_score_max_k(const int* __restrict__ ei, const float* __restrict__ als,
                                 const float* __restrict__ ald, float* __restrict__ ebuf,
                                 unsigned* __restrict__ mbuf, int E, int N)
{
    int eid = blockIdx.x * blockDim.x + threadIdx.x;
    if (eid >= E + N) return;
    int src = eid < E ? ei[eid] : eid - E;
    int dst = eid < E ? ei[E + eid] : eid - E;
    #pragma unroll
    for (int h = 0; h < NHD; ++h) {
        float e = als[src * NHD + h] + ald[dst * NHD + h];
        e = e > 0.f ? e : 0.2f * e;
        ebuf[(long)eid * NHD + h] = e;
        atomicMax(&mbuf[dst * NHD + h], enc_f32(e));
    }
}

__global__ void decode_max_k(unsigned* __restrict__ mbuf, int nh)
{
    int i = blockIdx.x * blockDim.x + threadIdx.x;
    if (i >= nh) return;
    unsigned u = mbuf[i];
    u = (u & 0x80000000u) ? (u & 0x7FFFFFFFu) : ~u;
    ((float*)mbuf)[i] = __uint_as_float(u);
}

// ---------------- ex = exp(e - m[dst]); den[dst] += ex ----------------
__global__ void edge_exp_k(const int* __restrict__ ei, const float* __restrict__ mf,
                           float* __restrict__ ebuf, float* __restrict__ den, int E, int N)
{
    int eid = blockIdx.x * blockDim.x + threadIdx.x;
    if (eid >= E + N) return;
    int dst = eid < E ? ei[E + eid] : eid - E;
    #pragma unroll
    for (int h = 0; h < NHD; ++h) {
        float ex = __expf(ebuf[(long)eid * NHD + h] - mf[dst * NHD + h]);
        ebuf[(long)eid * NHD + h] = ex;
        atomicAdd(&den[dst * NHD + h], ex);
    }
}

// ---------------- aggregation, concat layers (C=32, bf16 features) ----------------
__global__ __launch_bounds__(256)
void agg_cat_k(const int* __restrict__ ei, const unsigned short* __restrict__ xf,
               const float* __restrict__ ebuf, const float* __restrict__ den,
               float* __restrict__ agg, int E, int N)
{
    int eid = blockIdx.x;
    int tid = threadIdx.x;              // 0..255 = h*32+c
    int src = eid < E ? ei[eid] : eid - E;
    int dst = eid < E ? ei[E + eid] : eid - E;
    int h = tid >> 5;
    float alpha = ebuf[(long)eid * NHD + h] / (den[dst * NHD + h] + 1e-16f);
    float v = b2f(xf[(long)src * HID + tid]) * alpha;
    atomicAdd(&agg[(long)dst * HID + tid], v);
}

// ---------------- aggregation, mean layer (C=256, bf16, head-reduced) ----------------
__global__ __launch_bounds__(256)
void agg_mean_k(const int* __restrict__ ei, const unsigned short* __restrict__ xf,
                const float* __restrict__ ebuf, const float* __restrict__ den,
                float* __restrict__ agg, int E, int N)
{
    __shared__ float al[NHD];
    int eid = blockIdx.x;
    int tid = threadIdx.x;              // channel 0..255
    int src = eid < E ? ei[eid] : eid - E;
    int dst = eid < E ? ei[E + eid] : eid - E;
    if (tid < NHD) al[tid] = ebuf[(long)eid * NHD + tid] / (den[dst * NHD + tid] + 1e-16f);
    __syncthreads();
    const unsigned short* xp = xf + (long)src * (NHD * HID);
    float s = 0.f;
    #pragma unroll
    for (int h = 0; h < NHD; ++h)
        s += al[h] * b2f(xp[h * HID + tid]);
    atomicAdd(&agg[(long)dst * HID + tid], s * 0.125f);
}

// ---------------- BN stats ----------------
__global__ __launch_bounds__(256)
void stats_k(const float* __restrict__ agg, const float* __restrict__ bias,
             float* __restrict__ stats, int N)
{
    int c = threadIdx.x;
    int r0 = blockIdx.x * 100;
    int rend = r0 + 100; if (rend > N) rend = N;
    float b = bias[c];
    float s0 = 0.f, s1 = 0.f;
    for (int r = r0; r < rend; ++r) {
        float v = agg[(long)r * HID + c] + b;
        s0 += v; s1 += v * v;
    }
    atomicAdd(&stats[c], s0);
    atomicAdd(&stats[HID + c], s1);
}

__global__ void bnfin_k(float* __restrict__ stats, int N)
{
    int c = threadIdx.x;
    float mean = stats[c] / N;
    float var = stats[HID + c] / N - mean * mean;
    stats[c] = mean;
    stats[HID + c] = rsqrtf(var + 1e-5f);
}

// ---------------- BN apply (+bias) [+ELU +residual]; writes f32 and/or bf16 ----------------
template<bool ELU_RES>
__global__ void bnapply_k(const float* __restrict__ agg, const float* __restrict__ bias,
                          const float* __restrict__ stats, const float* __restrict__ g,
                          const float* __restrict__ be, const float* __restrict__ hprev,
                          float* __restrict__ hout, unsigned short* __restrict__ houtb,
                          int ldb, int N)
{
    long i = (long)blockIdx.x * blockDim.x + threadIdx.x;
    if (i >= (long)N * HID) return;
    int c = (int)(i & (HID - 1));
    int r = (int)(i >> 8);
    float v = agg[i] + bias[c];
    v = (v - stats[c]) * stats[HID + c] * g[c] + be[c];
    if (ELU_RES) {
        v = v > 0.f ? v : (__expf(v) - 1.f);
        v += hprev[i];
    }
    if (hout)  hout[i] = v;
    if (houtb) houtb[(long)r * ldb + c] = f2b(v);
}

// ---------------- final tiny GEMM: out[N,2] = z2[N,128] @ W3[128,2] + b3 ----------------
__global__ void final_k(const float* __restrict__ z2, const float* __restrict__ W,
                        const float* __restrict__ b, float* __restrict__ out, int N)
{
    int n = blockIdx.x * blockDim.x + threadIdx.x;
    if (n >= N) return;
    float a0 = b[0], a1 = b[1];
    const float* zp = z2 + (long)n * 128;
    #pragma unroll 4
    for (int k = 0; k < 128; ++k) { float z = zp[k]; a0 += z * W[k * 2]; a1 += z * W[k * 2 + 1]; }
    out[n * 2] = a0; out[n * 2 + 1] = a1;
}

extern "C" void kernel_launch(void* const* d_in, const int* in_sizes, int n_in,
                              void* d_out, int out_size, void* d_ws, size_t ws_size,
                              hipStream_t stream)
{
    const float* x   = (const float*)d_in[0];
    const int*   ei  = (const int*)d_in[1];
    const float* Wp  = (const float*)d_in[2];
    const float* bp  = (const float*)d_in[3];
    const float* W[3]   = {(const float*)d_in[4],  (const float*)d_in[10], (const float*)d_in[16]};
    const float* Asv[3] = {(const float*)d_in[5],  (const float*)d_in[11], (const float*)d_in[17]};
    const float* Adv[3] = {(const float*)d_in[6],  (const float*)d_in[12], (const float*)d_in[18]};
    const float* Bb[3]  = {(const float*)d_in[7],  (const float*)d_in[13], (const float*)d_in[19]};
    const float* Gg[3]  = {(const float*)d_in[8],  (const float*)d_in[14], (const float*)d_in[20]};
    const float* Be[3]  = {(const float*)d_in[9],  (const float*)d_in[15], (const float*)d_in[21]};
    const float* cW1 = (const float*)d_in[22];
    const float* cb1 = (const float*)d_in[23];
    const float* cW2 = (const float*)d_in[24];
    const float* cb2 = (const float*)d_in[25];
    const float* cW3 = (const float*)d_in[26];
    const float* cb3 = (const float*)d_in[27];

    const int F = in_sizes[2] / HID;      // 236
    const int N = in_sizes[0] / F;        // 20000
    const int E = in_sizes[1] / 2;        // 160000
    const int EP = E + N;
    const int Fpad = (F + 7) & ~7;        // 240

    float* ws   = (float*)d_ws;
    float* H0   = ws;                          // h_temporal f32 [N,256]
    float* H1   = H0 + (long)N * HID;          // layer0 out f32 [N,256]
    float* AGG  = H1 + (long)N * HID;          // [N,256]
    float* ALS  = AGG + (long)N * HID;         // [N,8]
    float* ALD  = ALS + (long)N * NHD;
    float* MBUF = ALD + (long)N * NHD;
    float* DEN  = MBUF + (long)N * NHD;
    float* EXF  = DEN + (long)N * NHD;         // [E',8]
    float* STATS= EXF + (long)EP * NHD;        // 512
    float* Z2   = STATS + 512;                 // [N,128] f32
    unsigned short* HCb = (unsigned short*)(Z2 + (long)N * 128);   // [N,512] bf16: [h3 | h_temporal]
    unsigned short* H1b = HCb + (long)N * 512;                     // [N,256]
    unsigned short* H2b = H1b + (long)N * HID;                     // [N,256]
    unsigned short* WpT = H2b + (long)N * HID;                     // [256,Fpad]
    unsigned short* W0T = WpT + 256L * Fpad;                       // [256,256]
    unsigned short* W1T = W0T + 256L * 256;
    unsigned short* W2T = W1T + 256L * 256;                        // [2048,256]
    unsigned short* cW1T = W2T + 2048L * 256;                      // [256,512]
    unsigned short* cW2T = cW1T + 256L * 512;                      // [128,256]
    unsigned short* XF   = cW2T + 128L * 256;                      // [N,2048] bf16 (layers share)
    unsigned short* xb   = XF;                                     // [N,Fpad] (dead after proj)
    unsigned short* Z1b  = XF;                                     // [N,256]  (classifier stage)

    const int mt = (N + 127) / 128;
    const int nhBlocks = (N * NHD + 255) / 256;
    const int naBlocks = (int)(((long)N * HID + 255) / 256);
    const int epBlocks = (EP + 255) / 256;
    const int statBlocks = (N + 99) / 100;

    // 0. convert weights (transpose to [Nc][K] bf16) and x
    cvtT_k<<<(int)((256L * Fpad + 255) / 256), 256, 0, stream>>>(Wp, WpT, F, Fpad, HID);
    cvtT_k<<<(int)((256L * 256 + 255) / 256), 256, 0, stream>>>(W[0], W0T, 256, 256, 256);
    cvtT_k<<<(int)((256L * 256 + 255) / 256), 256, 0, stream>>>(W[1], W1T, 256, 256, 256);
    cvtT_k<<<(int)((2048L * 256 + 255) / 256), 256, 0, stream>>>(W[2], W2T, 256, 256, 2048);
    cvtT_k<<<(int)((256L * 512 + 255) / 256), 256, 0, stream>>>(cW1, cW1T, 512, 512, 256);
    cvtT_k<<<(int)((128L * 256 + 255) / 256), 256, 0, stream>>>(cW2, cW2T, 256, 256, 128);
    cvtx_k<<<(int)(((long)N * Fpad + 255) / 256), 256, 0, stream>>>(x, xb, N, F, Fpad);

    // 1. input projection: H0(f32) + HCb[:,256:512](bf16) = x @ Wp + bp
    mgemm_k<true,false,true,true><<<dim3(2, mt), 256, 0, stream>>>(
        xb, Fpad, WpT, bp, H0, HID, HCb + 256, 512, N, HID, Fpad);

    // 2. GAT layers 0,1 (concat) + BN + ELU + residual
    for (int L = 0; L < 2; ++L) {
        const unsigned short* Ain = (L == 0) ? (HCb + 256) : H1b;
        int lda = (L == 0) ? 512 : 256;
        const unsigned short* WT = (L == 0) ? W0T : W1T;
        mgemm_k<false,false,false,true><<<dim3(2, mt), 256, 0, stream>>>(
            Ain, lda, WT, nullptr, nullptr, 0, XF, HID, N, HID, HID);
        attn_logits_k<<<nhBlocks, 256, 0, stream>>>(XF, Asv[L], Adv[L], ALS, ALD, N, 32);
        init_k<<<naBlocks, 256, 0, stream>>>((unsigned*)MBUF, DEN, AGG, STATS, N * NHD, (long)N * HID);
        edge_score_max_k<<<epBlocks, 256, 0, stream>>>(ei, ALS, ALD, EXF, (unsigned*)MBUF, E, N);
        decode_max_k<<<nhBlocks, 256, 0, stream>>>((unsigned*)MBUF, N * NHD);
        edge_exp_k<<<epBlocks, 256, 0, stream>>>(ei, MBUF, EXF, DEN, E, N);
        agg_cat_k<<<EP, 256, 0, stream>>>(ei, XF, EXF, DEN, AGG, E, N);
        stats_k<<<statBlocks, 256, 0, stream>>>(AGG, Bb[L], STATS, N);
        bnfin_k<<<1, 256, 0, stream>>>(STATS, N);
        if (L == 0)
            bnapply_k<true><<<naBlocks, 256, 0, stream>>>(AGG, Bb[0], STATS, Gg[0], Be[0], H0, H1, H1b, HID, N);
        else
            bnapply_k<true><<<naBlocks, 256, 0, stream>>>(AGG, Bb[1], STATS, Gg[1], Be[1], H1, nullptr, H2b, HID, N);
    }

    // 3. GAT layer 2 (mean over heads) + BN -> HCb[:,0:256] bf16
    mgemm_k<false,false,false,true><<<dim3(16, mt), 256, 0, stream>>>(
        H2b, HID, W2T, nullptr, nullptr, 0, XF, 2048, N, 2048, HID);
    attn_logits_k<<<nhBlocks, 256, 0, stream>>>(XF, Asv[2], Adv[2], ALS, ALD, N, HID);
    init_k<<<naBlocks, 256, 0, stream>>>((unsigned*)MBUF, DEN, AGG, STATS, N * NHD, (long)N * HID);
    edge_score_max_k<<<epBlocks, 256, 0, stream>>>(ei, ALS, ALD, EXF, (unsigned*)MBUF, E, N);
    decode_max_k<<<nhBlocks, 256, 0, stream>>>((unsigned*)MBUF, N * NHD);
    edge_exp_k<<<epBlocks, 256, 0, stream>>>(ei, MBUF, EXF, DEN, E, N);
    agg_mean_k<<<EP, 256, 0, stream>>>(ei, XF, EXF, DEN, AGG, E, N);
    stats_k<<<statBlocks, 256, 0, stream>>>(AGG, Bb[2], STATS, N);
    bnfin_k<<<1, 256, 0, stream>>>(STATS, N);
    bnapply_k<false><<<naBlocks, 256, 0, stream>>>(AGG, Bb[2], STATS, Gg[2], Be[2], nullptr, nullptr, HCb, 512, N);

    // 4. classifier: z1 = relu(HCb[N,512] @ cW1 + cb1) -> Z1b bf16
    mgemm_k<true,true,false,true><<<dim3(2, mt), 256, 0, stream>>>(
        HCb, 512, cW1T, cb1, nullptr, 0, Z1b, HID, N, HID, 512);
    // z2 = relu(z1 @ cW2 + cb2) -> Z2 f32
    mgemm_k<true,true,true,false><<<dim3(1, mt), 256, 0, stream>>>(
        Z1b, HID, cW2T, cb2, Z2, 128, nullptr, 0, N, 128, HID);
    // out = z2 @ cW3 + cb3
    final_k<<<(N + 255) / 256, 256, 0, stream>>>(Z2, cW3, cb3, (float*)d_out, N);
}

// Round 3
// 642.911 us; speedup vs baseline: 3.3319x; 1.9827x over previous
//
#include <hip/hip_runtime.h>
#include <hip/hip_bf16.h>

#define HID 256
#define NHD 8

typedef short short8 __attribute__((ext_vector_type(8)));
typedef float f32x4 __attribute__((ext_vector_type(4)));

__device__ __forceinline__ float b2f(unsigned short u) {
    return __uint_as_float(((unsigned)u) << 16);
}
__device__ __forceinline__ unsigned short f2b(float f) {
    __hip_bfloat16 h = __float2bfloat16(f);
    return *reinterpret_cast<unsigned short*>(&h);
}

// ---------------- weight convert+transpose: WT[n*Kpad+k] = bf16(W[k*Nc+n]) ----------------
__global__ void cvtT_k(const float* __restrict__ W, unsigned short* __restrict__ WT,
                       int K, int Kpad, int Nc)
{
    long i = (long)blockIdx.x * blockDim.x + threadIdx.x;
    if (i >= (long)Nc * Kpad) return;
    int n = (int)(i / Kpad), k = (int)(i % Kpad);
    WT[i] = (k < K) ? f2b(W[(long)k * Nc + n]) : (unsigned short)0;
}

// B2T[n*2048 + c*8 + h] = bf16(W2[c, h*256+n] / 8)
__global__ void cvtW2_k(const float* __restrict__ W2, unsigned short* __restrict__ BT)
{
    long i = (long)blockIdx.x * blockDim.x + threadIdx.x;
    if (i >= 256L * 2048) return;
    int n = (int)(i >> 11);
    int q = (int)(i & 2047);
    int c = q >> 3, h = q & 7;
    BT[i] = f2b(W2[(long)c * 2048 + h * 256 + n] * 0.125f);
}

// WS[h*256+k] = sum_c W2[k, h*256+c] * as2[h,c]  (and WD with ad2)
__global__ void prep_ws_k(const float* __restrict__ W2, const float* __restrict__ as2,
                          const float* __restrict__ ad2, float* __restrict__ WS,
                          float* __restrict__ WD)
{
    int i = blockIdx.x * blockDim.x + threadIdx.x;   // h*256+k
    if (i >= 2048) return;
    int h = i >> 8, k = i & 255;
    float s = 0.f, d = 0.f;
    for (int c = 0; c < 256; ++c) {
        float w = W2[(long)k * 2048 + h * 256 + c];
        s += w * as2[h * 256 + c];
        d += w * ad2[h * 256 + c];
    }
    WS[i] = s; WD[i] = d;
}

// ---------------- x convert with row pad ----------------
__global__ void cvtx_k(const float* __restrict__ x, unsigned short* __restrict__ xb,
                       int N, int F, int Fpad)
{
    long i = (long)blockIdx.x * blockDim.x + threadIdx.x;
    if (i >= (long)N * Fpad) return;
    int r = (int)(i / Fpad), c = (int)(i % Fpad);
    xb[i] = (c < F) ? f2b(x[(long)r * F + c]) : (unsigned short)0;
}

// ---------------- CSR build ----------------
__global__ void inith_k(int* __restrict__ hist, int* __restrict__ cnt, int N)
{
    int i = blockIdx.x * blockDim.x + threadIdx.x;
    if (i < N) { hist[i] = 1; cnt[i] = 0; }   // 1 = self-loop
}

__global__ void count_k(const int* __restrict__ ei, int* __restrict__ hist, int E)
{
    int e = blockIdx.x * blockDim.x + threadIdx.x;
    if (e < E) atomicAdd(&hist[ei[E + e]], 1);
}

__global__ __launch_bounds__(1024)
void scan_k(const int* __restrict__ hist, int* __restrict__ rowptr, int N, int CH)
{
    __shared__ int part[1024];
    int t = threadIdx.x;
    long base = (long)t * CH;
    int s = 0;
    for (int j = 0; j < CH; ++j) {
        long idx = base + j;
        if (idx < N) s += hist[idx];
    }
    part[t] = s;
    __syncthreads();
    for (int off = 1; off < 1024; off <<= 1) {
        int v = (t >= off) ? part[t - off] : 0;
        __syncthreads();
        part[t] += v;
        __syncthreads();
    }
    int pre = (t > 0) ? part[t - 1] : 0;
    for (int j = 0; j < CH; ++j) {
        long idx = base + j;
        if (idx < N) { rowptr[idx] = pre; pre += hist[idx]; }
    }
    if (t == 1023) rowptr[N] = part[1023];
}

__global__ void fill_k(const int* __restrict__ ei, const int* __restrict__ rowptr,
                       int* __restrict__ cnt, int* __restrict__ csr, int E, int N)
{
    int e = blockIdx.x * blockDim.x + threadIdx.x;
    if (e >= E + N) return;
    int src = e < E ? ei[e] : e - E;
    int dst = e < E ? ei[E + e] : e - E;
    int pos = rowptr[dst] + atomicAdd(&cnt[dst], 1);
    csr[pos] = src;
}

// ---------------- MFMA GEMM: C[M,Nc] = A[M,K](bf16) @ BT[Nc,K](bf16)^T ----------------
template<bool BIAS, bool RELU, bool OUTF, bool OUTB>
__global__ __launch_bounds__(256)
void mgemm_k(const unsigned short* __restrict__ A, int lda,
             const unsigned short* __restrict__ BT,
             const float* __restrict__ bias,
             float* __restrict__ Cf, int ldf,
             unsigned short* __restrict__ Cb, int ldb,
             int M, int Nc, int K)
{
    __shared__ unsigned short As[128 * 32];
    __shared__ unsigned short Bs[128 * 32];
    const int tid = threadIdx.x;
    const int lane = tid & 63, wid = tid >> 6;
    const int wm = wid >> 1, wn = wid & 1;
    const int lr = lane & 15, lg = lane >> 4;
    const int row0 = blockIdx.y * 128, col0 = blockIdx.x * 128;
    f32x4 acc[4][4] = {};

    for (int k0 = 0; k0 < K; k0 += 32) {
        __syncthreads();
        #pragma unroll
        for (int c = 0; c < 2; ++c) {
            int chunk = tid * 2 + c;
            int r = chunk >> 2, kc = (chunk & 3) * 8;
            int idx = (r * 32 + kc) ^ ((r & 7) << 3);
            int gk = k0 + kc;
            int gr = row0 + r;
            int4 va;
            if (gr < M && gk + 8 <= K) va = *(const int4*)(A + (long)gr * lda + gk);
            else {
                unsigned short tmp[8];
                #pragma unroll
                for (int j = 0; j < 8; ++j)
                    tmp[j] = (gr < M && gk + j < K) ? A[(long)gr * lda + gk + j] : (unsigned short)0;
                va = *(const int4*)tmp;
            }
            *(int4*)(&As[idx]) = va;
            int gn = col0 + r;
            int4 vb;
            if (gk + 8 <= K) vb = *(const int4*)(BT + (long)gn * K + gk);
            else {
                unsigned short tmp[8];
                #pragma unroll
                for (int j = 0; j < 8; ++j)
                    tmp[j] = (gk + j < K) ? BT[(long)gn * K + gk + j] : (unsigned short)0;
                vb = *(const int4*)tmp;
            }
            *(int4*)(&Bs[idx]) = vb;
        }
        __syncthreads();
        short8 af[4], bfr[4];
        #pragma unroll
        for (int m = 0; m < 4; ++m) {
            int row = wm * 64 + m * 16 + lr;
            int idx = (row * 32 + lg * 8) ^ ((row & 7) << 3);
            af[m] = *(const short8*)(&As[idx]);
        }
        #pragma unroll
        for (int n = 0; n < 4; ++n) {
            int rowb = wn * 64 + n * 16 + lr;
            int idx = (rowb * 32 + lg * 8) ^ ((rowb & 7) << 3);
            bfr[n] = *(const short8*)(&Bs[idx]);
        }
        #pragma unroll
        for (int m = 0; m < 4; ++m)
            #pragma unroll
            for (int n = 0; n < 4; ++n)
                acc[m][n] = __builtin_amdgcn_mfma_f32_16x16x32_bf16(af[m], bfr[n], acc[m][n], 0, 0, 0);
    }
    #pragma unroll
    for (int m = 0; m < 4; ++m) {
        #pragma unroll
        for (int i = 0; i < 4; ++i) {
            int row = row0 + wm * 64 + m * 16 + lg * 4 + i;
            if (row >= M) continue;
            #pragma unroll
            for (int n = 0; n < 4; ++n) {
                int col = col0 + wn * 64 + n * 16 + lr;
                float v = acc[m][n][i];
                if (BIAS) v += bias[col];
                if (RELU) v = v > 0.f ? v : 0.f;
                if (OUTF) Cf[(long)row * ldf + col] = v;
                if (OUTB) Cb[(long)row * ldb + col] = f2b(v);
            }
        }
    }
}

// ---------------- attention logits, layers 0/1 (Cc=32 per head) ----------------
__global__ void attn_logits_k(const unsigned short* __restrict__ xf, const float* __restrict__ a_s,
                              const float* __restrict__ a_d, float* __restrict__ als,
                              float* __restrict__ ald, int N, int Cc)
{
    int nh = blockIdx.x * blockDim.x + threadIdx.x;
    if (nh >= N * NHD) return;
    int n = nh >> 3, h = nh & 7;
    const unsigned short* xp = xf + (long)n * NHD * Cc + h * Cc;
    const float* asp = a_s + h * Cc;
    const float* adp = a_d + h * Cc;
    float s = 0.f, d = 0.f;
    for (int c = 0; c < Cc; c += 8) {
        short8 v = *(const short8*)(xp + c);
        #pragma unroll
        for (int j = 0; j < 8; ++j) {
            float f = b2f((unsigned short)v[j]);
            s += f * asp[c + j]; d += f * adp[c + j];
        }
    }
    als[nh] = s; ald[nh] = d;
}

// ---------------- attention logits, layer 2 (folded: h_in @ WS/WD) ----------------
__global__ void attn2_k(const unsigned short* __restrict__ xb, const float* __restrict__ WS,
                        const float* __restrict__ WD, float* __restrict__ als,
                        float* __restrict__ ald, int N)
{
    int nh = blockIdx.x * blockDim.x + threadIdx.x;
    if (nh >= N * NHD) return;
    int n = nh >> 3, h = nh & 7;
    const unsigned short* xp = xb + (long)n * 256;
    const float* wsp = WS + h * 256;
    const float* wdp = WD + h * 256;
    float s = 0.f, d = 0.f;
    for (int k = 0; k < 256; k += 8) {
        short8 v = *(const short8*)(xp + k);
        #pragma unroll
        for (int j = 0; j < 8; ++j) {
            float f = b2f((unsigned short)v[j]);
            s += f * wsp[k + j]; d += f * wdp[k + j];
        }
    }
    als[nh] = s; ald[nh] = d;
}

// ---------------- softmax stats per (dst,head): Mv=max, Bv=1/(den+eps); zeroes STATS ----------------
__global__ void sm_k(const int* __restrict__ rowptr, const int* __restrict__ csr,
                     const float* __restrict__ als, const float* __restrict__ ald,
                     float* __restrict__ Mv, float* __restrict__ Bv,
                     float* __restrict__ stats, int N)
{
    int nh = blockIdx.x * blockDim.x + threadIdx.x;
    if (nh < 512) stats[nh] = 0.f;
    if (nh >= N * NHD) return;
    int d = nh >> 3, h = nh & 7;
    int p0 = rowptr[d], p1 = rowptr[d + 1];
    float av = ald[nh];
    float m = -1e30f;
    for (int p = p0; p < p1; ++p) {
        float e = als[csr[p] * NHD + h] + av;
        e = e > 0.f ? e : 0.2f * e;
        m = fmaxf(m, e);
    }
    float den = 0.f;
    for (int p = p0; p < p1; ++p) {
        float e = als[csr[p] * NHD + h] + av;
        e = e > 0.f ? e : 0.2f * e;
        den += __expf(e - m);
    }
    Mv[nh] = m;
    Bv[nh] = 1.f / (den + 1e-16f);
}

// ---------------- aggregation, layers 0/1: block per dst, write-once ----------------
__global__ __launch_bounds__(256)
void agg01_k(const int* __restrict__ rowptr, const int* __restrict__ csr,
             const unsigned short* __restrict__ xf,
             const float* __restrict__ als, const float* __restrict__ ald,
             const float* __restrict__ Mv, const float* __restrict__ Bv,
             float* __restrict__ agg)
{
    int d = blockIdx.x;
    int c = threadIdx.x;
    int h = c >> 5;
    int p0 = rowptr[d], p1 = rowptr[d + 1];
    float av = ald[d * NHD + h], mh = Mv[d * NHD + h], bh = Bv[d * NHD + h];
    float acc = 0.f;
    for (int p = p0; p < p1; ++p) {
        int s = csr[p];
        float e = als[s * NHD + h] + av;
        e = e > 0.f ? e : 0.2f * e;
        float a = __expf(e - mh) * bh;
        acc += a * b2f(xf[(long)s * HID + c]);
    }
    agg[(long)d * HID + c] = acc;
}

// ---------------- aggregation, layer 2 input-space: AGG8[d, k*8+h] = sum_e alpha_eh h_in[src,k] ----------------
__global__ __launch_bounds__(256)
void agg2_k(const int* __restrict__ rowptr, const int* __restrict__ csr,
            const unsigned short* __restrict__ xb,
            const float* __restrict__ als, const float* __restrict__ ald,
            const float* __restrict__ Mv, const float* __restrict__ Bv,
            unsigned short* __restrict__ agg8)
{
    __shared__ float aL[32][NHD];
    __shared__ int   sL[32];
    int d = blockIdx.x;
    int c = threadIdx.x;
    int p0 = rowptr[d], p1 = rowptr[d + 1];
    float acc[NHD] = {};
    for (int pc = p0; pc < p1; pc += 32) {
        int nedge = p1 - pc; if (nedge > 32) nedge = 32;
        {
            int j = c >> 3, h = c & 7;
            if (j < nedge) {
                int s = csr[pc + j];
                if (h == 0) sL[j] = s;
                float e = als[s * NHD + h] + ald[d * NHD + h];
                e = e > 0.f ? e : 0.2f * e;
                aL[j][h] = __expf(e - Mv[d * NHD + h]) * Bv[d * NHD + h];
            }
        }
        __syncthreads();
        for (int j = 0; j < nedge; ++j) {
            float v = b2f(xb[(long)sL[j] * HID + c]);
            #pragma unroll
            for (int h = 0; h < NHD; ++h) acc[h] += aL[j][h] * v;
        }
        __syncthreads();
    }
    unsigned short ob[NHD];
    #pragma unroll
    for (int h = 0; h < NHD; ++h) ob[h] = f2b(acc[h]);
    *(int4*)(agg8 + (long)d * 2048 + c * 8) = *(const int4*)ob;
}

// ---------------- BN stats ----------------
__global__ __launch_bounds__(256)
void stats_k(const float* __restrict__ agg, const float* __restrict__ bias,
             float* __restrict__ stats, int N)
{
    int c = threadIdx.x;
    int r0 = blockIdx.x * 100;
    int rend = r0 + 100; if (rend > N) rend = N;
    float b = bias[c];
    float s0 = 0.f, s1 = 0.f;
    for (int r = r0; r < rend; ++r) {
        float v = agg[(long)r * HID + c] + b;
        s0 += v; s1 += v * v;
    }
    atomicAdd(&stats[c], s0);
    atomicAdd(&stats[HID + c], s1);
}

__global__ void bnfin_k(float* __restrict__ stats, int N)
{
    int c = threadIdx.x;
    float mean = stats[c] / N;
    float var = stats[HID + c] / N - mean * mean;
    stats[c] = mean;
    stats[HID + c] = rsqrtf(var + 1e-5f);
}

// ---------------- BN apply (+bias) [+ELU +residual] ----------------
template<bool ELU_RES>
__global__ void bnapply_k(const float* __restrict__ agg, const float* __restrict__ bias,
                          const float* __restrict__ stats, const float* __restrict__ g,
                          const float* __restrict__ be, const float* __restrict__ hprev,
                          float* __restrict__ hout, unsigned short* __restrict__ houtb,
                          int ldb, int N)
{
    long i = (long)blockIdx.x * blockDim.x + threadIdx.x;
    if (i >= (long)N * HID) return;
    int c = (int)(i & (HID - 1));
    int r = (int)(i >> 8);
    float v = agg[i] + bias[c];
    v = (v - stats[c]) * stats[HID + c] * g[c] + be[c];
    if (ELU_RES) {
        v = v > 0.f ? v : (__expf(v) - 1.f);
        v += hprev[i];
    }
    if (hout)  hout[i] = v;
    if (houtb) houtb[(long)r * ldb + c] = f2b(v);
}

// ---------------- final tiny GEMM ----------------
__global__ void final_k(const float* __restrict__ z2, const float* __restrict__ W,
                        const float* __restrict__ b, float* __restrict__ out, int N)
{
    int n = blockIdx.x * blockDim.x + threadIdx.x;
    if (n >= N) return;
    float a0 = b[0], a1 = b[1];
    const float* zp = z2 + (long)n * 128;
    #pragma unroll 4
    for (int k = 0; k < 128; ++k) { float z = zp[k]; a0 += z * W[k * 2]; a1 += z * W[k * 2 + 1]; }
    out[n * 2] = a0; out[n * 2 + 1] = a1;
}

extern "C" void kernel_launch(void* const* d_in, const int* in_sizes, int n_in,
                              void* d_out, int out_size, void* d_ws, size_t ws_size,
                              hipStream_t stream)
{
    const float* x   = (const float*)d_in[0];
    const int*   ei  = (const int*)d_in[1];
    const float* Wp  = (const float*)d_in[2];
    const float* bp  = (const float*)d_in[3];
    const float* W[3]   = {(const float*)d_in[4],  (const float*)d_in[10], (const float*)d_in[16]};
    const float* Asv[3] = {(const float*)d_in[5],  (const float*)d_in[11], (const float*)d_in[17]};
    const float* Adv[3] = {(const float*)d_in[6],  (const float*)d_in[12], (const float*)d_in[18]};
    const float* Bb[3]  = {(const float*)d_in[7],  (const float*)d_in[13], (const float*)d_in[19]};
    const float* Gg[3]  = {(const float*)d_in[8],  (const float*)d_in[14], (const float*)d_in[20]};
    const float* Be[3]  = {(const float*)d_in[9],  (const float*)d_in[15], (const float*)d_in[21]};
    const float* cW1 = (const float*)d_in[22];
    const float* cb1 = (const float*)d_in[23];
    const float* cW2 = (const float*)d_in[24];
    const float* cb2 = (const float*)d_in[25];
    const float* cW3 = (const float*)d_in[26];
    const float* cb3 = (const float*)d_in[27];

    const int F = in_sizes[2] / HID;      // 236
    const int N = in_sizes[0] / F;        // 20000
    const int E = in_sizes[1] / 2;        // 160000
    const int EP = E + N;
    const int Fpad = (F + 7) & ~7;        // 240

    float* ws   = (float*)d_ws;
    float* H0   = ws;                          // h_temporal f32 [N,256]
    float* H1   = H0 + (long)N * HID;          // layer0 out f32 [N,256]
    float* AGG  = H1 + (long)N * HID;          // [N,256]
    float* ALS  = AGG + (long)N * HID;         // [N,8]
    float* ALD  = ALS + (long)N * NHD;
    float* MV   = ALD + (long)N * NHD;
    float* BV   = MV  + (long)N * NHD;
    float* STATS= BV  + (long)N * NHD;         // 512
    float* WS   = STATS + 512;                 // [8,256]
    float* WD   = WS + 2048;                   // [8,256]
    float* Z2   = WD + 2048;                   // [N,128] f32
    unsigned short* HCb = (unsigned short*)(Z2 + (long)N * 128);   // [N,512] bf16: [h3 | h_temporal]
    unsigned short* H1b = HCb + (long)N * 512;                     // [N,256]
    unsigned short* H2b = H1b + (long)N * HID;                     // [N,256]
    unsigned short* WpT = H2b + (long)N * HID;                     // [256,Fpad]
    unsigned short* W0T = WpT + 256L * Fpad;                       // [256,256]
    unsigned short* W1T = W0T + 256L * 256;
    unsigned short* B2T = W1T + 256L * 256;                        // [256,2048] permuted W2/8
    unsigned short* cW1T = B2T + 256L * 2048;                      // [256,512]
    unsigned short* cW2T = cW1T + 256L * 512;                      // [128,256]
    unsigned short* XF   = cW2T + 128L * 256;                      // [N,256] bf16 (layer 0/1 feats)
    unsigned short* AGG8 = XF + (long)N * HID;                     // [N,2048] bf16
    unsigned short* xb   = AGG8;                                   // [N,Fpad] (dead before agg2 use)
    unsigned short* Z1b  = XF;                                     // [N,256] (classifier stage)
    int* rowptr = (int*)(AGG8 + (long)N * 2048);                   // [N+1]
    int* cnt    = rowptr + (N + 1);                                // [N]
    int* csr    = cnt + N;                                         // [EP]

    const int mt = (N + 127) / 128;
    const int nhBlocks = (N * NHD + 255) / 256;
    const int naBlocks = (int)(((long)N * HID + 255) / 256);
    const int statBlocks = (N + 99) / 100;
    const int CH = (N + 1023) / 1024;

    // 0a. CSR build (order within a dst bucket is arbitrary -> 1e-6 sum noise only)
    inith_k<<<(N + 255) / 256, 256, 0, stream>>>(rowptr + (N + 1), rowptr + (N + 1), N); // dummy? no:
    // (use cnt/hist properly)
    inith_k<<<(N + 255) / 256, 256, 0, stream>>>(cnt, cnt, N);
    // hist lives in `cnt` temporarily? Need separate hist + cnt: reuse MV as hist (int-punned)
    {
        int* hist = (int*)MV;  // [N] ints fit in MV [N*8] floats
        inith_k<<<(N + 255) / 256, 256, 0, stream>>>(hist, cnt, N);
        count_k<<<(E + 255) / 256, 256, 0, stream>>>(ei, hist, E);
        scan_k<<<1, 1024, 0, stream>>>(hist, rowptr, N, CH);
        fill_k<<<(EP + 255) / 256, 256, 0, stream>>>(ei, rowptr, cnt, csr, E, N);
    }

    // 0b. convert weights and x
    cvtT_k<<<(int)((256L * Fpad + 255) / 256), 256, 0, stream>>>(Wp, WpT, F, Fpad, HID);
    cvtT_k<<<(int)((256L * 256 + 255) / 256), 256, 0, stream>>>(W[0], W0T, 256, 256, 256);
    cvtT_k<<<(int)((256L * 256 + 255) / 256), 256, 0, stream>>>(W[1], W1T, 256, 256, 256);
    cvtW2_k<<<(int)((256L * 2048 + 255) / 256), 256, 0, stream>>>(W[2], B2T);
    prep_ws_k<<<8, 256, 0, stream>>>(W[2], Asv[2], Adv[2], WS, WD);
    cvtT_k<<<(int)((256L * 512 + 255) / 256), 256, 0, stream>>>(cW1, cW1T, 512, 512, 256);
    cvtT_k<<<(int)((128L * 256 + 255) / 256), 256, 0, stream>>>(cW2, cW2T, 256, 256, 128);
    cvtx_k<<<(int)(((long)N * Fpad + 255) / 256), 256, 0, stream>>>(x, xb, N, F, Fpad);

    // 1. input projection: H0(f32) + HCb[:,256:512](bf16) = x @ Wp + bp
    mgemm_k<true,false,true,true><<<dim3(2, mt), 256, 0, stream>>>(
        xb, Fpad, WpT, bp, H0, HID, HCb + 256, 512, N, HID, Fpad);

    // 2. GAT layers 0,1 (concat) + BN + ELU + residual
    for (int L = 0; L < 2; ++L) {
        const unsigned short* Ain = (L == 0) ? (HCb + 256) : H1b;
        int lda = (L == 0) ? 512 : 256;
        const unsigned short* WT = (L == 0) ? W0T : W1T;
        mgemm_k<false,false,false,true><<<dim3(2, mt), 256, 0, stream>>>(
            Ain, lda, WT, nullptr, nullptr, 0, XF, HID, N, HID, HID);
        attn_logits_k<<<nhBlocks, 256, 0, stream>>>(XF, Asv[L], Adv[L], ALS, ALD, N, 32);
        sm_k<<<nhBlocks, 256, 0, stream>>>(rowptr, csr, ALS, ALD, MV, BV, STATS, N);
        agg01_k<<<N, 256, 0, stream>>>(rowptr, csr, XF, ALS, ALD, MV, BV, AGG);
        stats_k<<<statBlocks, 256, 0, stream>>>(AGG, Bb[L], STATS, N);
        bnfin_k<<<1, 256, 0, stream>>>(STATS, N);
        if (L == 0)
            bnapply_k<true><<<naBlocks, 256, 0, stream>>>(AGG, Bb[0], STATS, Gg[0], Be[0], H0, H1, H1b, HID, N);
        else
            bnapply_k<true><<<naBlocks, 256, 0, stream>>>(AGG, Bb[1], STATS, Gg[1], Be[1], H1, nullptr, H2b, HID, N);
    }

    // 3. GAT layer 2, aggregate-then-transform
    attn2_k<<<nhBlocks, 256, 0, stream>>>(H2b, WS, WD, ALS, ALD, N);
    sm_k<<<nhBlocks, 256, 0, stream>>>(rowptr, csr, ALS, ALD, MV, BV, STATS, N);
    agg2_k<<<N, 256, 0, stream>>>(rowptr, csr, H2b, ALS, ALD, MV, BV, AGG8);
    mgemm_k<false,false,true,false><<<dim3(2, mt), 256, 0, stream>>>(
        AGG8, 2048, B2T, nullptr, AGG, HID, nullptr, 0, N, HID, 2048);
    stats_k<<<statBlocks, 256, 0, stream>>>(AGG, Bb[2], STATS, N);
    bnfin_k<<<1, 256, 0, stream>>>(STATS, N);
    bnapply_k<false><<<naBlocks, 256, 0, stream>>>(AGG, Bb[2], STATS, Gg[2], Be[2], nullptr, nullptr, HCb, 512, N);

    // 4. classifier
    mgemm_k<true,true,false,true><<<dim3(2, mt), 256, 0, stream>>>(
        HCb, 512, cW1T, cb1, nullptr, 0, Z1b, HID, N, HID, 512);
    mgemm_k<true,true,true,false><<<dim3(1, mt), 256, 0, stream>>>(
        Z1b, HID, cW2T, cb2, Z2, 128, nullptr, 0, N, 128, HID);
    final_k<<<(N + 255) / 256, 256, 0, stream>>>(Z2, cW3, cb3, (float*)d_out, N);
}